// Round 8
// baseline (214.160 us; speedup 1.0000x reference)
//
#include <hip/hip_runtime.h>

#define N_PTS 32768
#define M_PTS 8192      // N / STRIDE
#define C_IN  64
#define C_OUT 128
#define KNN   16
#define GDIM  67        // 3 + C_IN
#define BN_EPS 1e-5f
#define MAXC  64        // centers with candidate-buffer fast path

// workspace offsets (bytes)
#define OFF_FPS   0u          // int[M_PTS] (only first nuniq used)
#define OFF_META  163840u     // int[8]: [0]=nuniq [1]=cycStart [2]=cycLen
#define OFF_KNN   163904u     // int[M_PTS*KNN] (fallback use only)
#define OFF_CAND  688192u     // u64[MAXC*2048]

typedef unsigned int uint32;
typedef unsigned long long uint64;

// multiplicity of unique slot s in the length-M periodic index sequence
__device__ __forceinline__ int slot_count(int s, int nun, int cs, int cl, int M) {
    if (s < cs) return 1;                 // pre-cycle slot: occurs once
    const int E = M - nun;                // extended (periodic) occurrences
    const int base = E / cl, rem = E % cl;
    const int start = (nun - cs) % cl;    // residue of first extended index
    int off = (s - cs) - start; if (off < 0) off += cl;
    return 1 + base + (off < rem ? 1 : 0);
}

__device__ __forceinline__ uint32 dist_key(float d) {
    uint32 u = __float_as_uint(d);
    return (u & 0x80000000u) ? ~u : (u | 0x80000000u);
}

// ---------------- FPS chain only: serial argmax steps, LDS chain ----------------
__global__ void __launch_bounds__(1024) fps_chain_kernel(const float* __restrict__ p,
                                                         int* __restrict__ fps,
                                                         int* __restrict__ meta) {
    __shared__ int   s_chain[M_PTS];     // 32 KB
    __shared__ float wv_d[16];
    __shared__ int   wv_i[16];
    __shared__ int s_last, s_done, s_cs, s_win, s_found;
    const int tid  = threadIdx.x;
    const int lane = tid & 63;
    const int wid  = tid >> 6;

    if (tid == 0) { s_chain[0] = 0; s_last = 0; s_done = 0; s_cs = 0; }
    __syncthreads();

    int t = 1;
    while (t < M_PTS) {
        const int last = s_last;
        const float qx = p[3*last], qy = p[3*last+1], qz = p[3*last+2];
        float bd = -1.0f; int bi = 0;
#pragma unroll
        for (int j = 0; j < 32; ++j) {
            const int i = tid + (j << 10);
            // match numpy: ((dx^2 + dy^2) + dz^2), no FMA contraction
            float dx = __fsub_rn(p[3*i],   qx);
            float dy = __fsub_rn(p[3*i+1], qy);
            float dz = __fsub_rn(p[3*i+2], qz);
            float d  = __fadd_rn(__fadd_rn(__fmul_rn(dx,dx), __fmul_rn(dy,dy)),
                                 __fmul_rn(dz,dz));
            if (d > bd) { bd = d; bi = i; }   // ascending i keeps first on ties
        }
#pragma unroll
        for (int off = 32; off > 0; off >>= 1) {
            float od = __shfl_xor(bd, off);
            int   oi = __shfl_xor(bi, off);
            if (od > bd || (od == bd && oi < bi)) { bd = od; bi = oi; }
        }
        if (lane == 0) { wv_d[wid] = bd; wv_i[wid] = bi; }
        __syncthreads();
        if (wid == 0) {
            float rd = (lane < 16) ? wv_d[lane] : -1.0f;
            int   ri = (lane < 16) ? wv_i[lane] : 0x7fffffff;
#pragma unroll
            for (int off = 8; off > 0; off >>= 1) {
                float od = __shfl_xor(rd, off);
                int   oi = __shfl_xor(ri, off);
                if (od > rd || (od == rd && oi < ri)) { rd = od; ri = oi; }
            }
            if (lane == 0) { s_win = ri; s_found = -1; }
        }
        __syncthreads();
        const int nxt = s_win;
        for (int i = tid; i < t; i += 1024)
            if (s_chain[i] == nxt) s_found = i;
        __syncthreads();
        if (tid == 0) {
            if (s_found >= 0) { s_cs = s_found; s_done = 1; }
            else { s_chain[t] = nxt; s_last = nxt; }
        }
        __syncthreads();
        if (s_done) break;
        ++t;
    }

    if (tid == 0) {
        if (s_done) { meta[0] = t; meta[1] = s_cs; meta[2] = t - s_cs; }
        else        { meta[0] = M_PTS; meta[1] = 0; meta[2] = 1; }
    }
    const int nun = s_done ? t : M_PTS;
    for (int i = tid; i < nun; i += 1024) fps[i] = s_chain[i];
}

// ---- kNN phase A (+ parallel newp fill): 8 slices/center, per-wave top-16 ------
__global__ void __launch_bounds__(1024) knn_part_kernel(const float* __restrict__ p,
                                                        const int* __restrict__ fps,
                                                        const int* __restrict__ meta,
                                                        uint64* __restrict__ cand,
                                                        float* __restrict__ newp) {
    const int tid   = threadIdx.x;
    const int lane  = tid & 63;
    const int wid   = tid >> 6;           // 16 waves
    const int slice = blockIdx.x & 7;
    const int c0    = blockIdx.x >> 3;    // 16 center groups
    const int nun   = meta[0];
    const int cs    = meta[1], cl = meta[2];

    // parallel newp fill
    for (int e = blockIdx.x * 1024 + tid; e < M_PTS; e += gridDim.x * 1024) {
        const int sl = (e < nun) ? e : cs + (e - cs) % cl;
        const int id = fps[sl];
        newp[3*e]   = p[3*id];
        newp[3*e+1] = p[3*id+1];
        newp[3*e+2] = p[3*id+2];
    }

    for (int c = c0; c < nun && c < MAXC; c += 16) {
        const int cpt = fps[c];
        const float qx = p[3*cpt], qy = p[3*cpt+1], qz = p[3*cpt+2];
        const int base = slice << 12;     // slice*4096

        uint64 pk4[4];
#pragma unroll
        for (int j = 0; j < 4; ++j) {
            const int i = base + tid + (j << 10);
            float dx = p[3*i]   - qx;
            float dy = p[3*i+1] - qy;
            float dz = p[3*i+2] - qz;
            float d  = fmaf(dx, dx, fmaf(dy, dy, dz*dz));
            pk4[j] = ((uint64)dist_key(d) << 32) | (uint32)i;
        }

        uint64 lastv = 0ull;
        uint64* out = cand + ((size_t)c << 11) + (slice << 8) + (wid << 4);
        for (int r = 0; r < KNN; ++r) {
            uint64 m = ~0ull;
#pragma unroll
            for (int j = 0; j < 4; ++j) {
                const uint64 v = pk4[j];
                if (v > lastv && v < m) m = v;
            }
#pragma unroll
            for (int off = 32; off > 0; off >>= 1) {
                uint64 o = __shfl_xor(m, off);
                if (o < m) m = o;
            }
            if (lane == 0) out[r] = m;
            lastv = m;
        }
    }
}

// ---- fused tail: merge candidates + stats + BN + pooled output rows -----------
// One block, 1024 threads = 8 groups x 128. Group g merges/owns slot chunk*8+g;
// thread (g, l) owns channel l of that slot. h kept in registers (single-chunk
// fast path); deterministic fixed-order LDS reductions; uniform barriers.
__global__ void __launch_bounds__(1024) tail_kernel(const float* __restrict__ p,
                                                    const float* __restrict__ x,
                                                    const float* __restrict__ W,
                                                    const float* __restrict__ gamma,
                                                    const float* __restrict__ beta,
                                                    const int* __restrict__ fps,
                                                    const int* __restrict__ meta,
                                                    const uint64* __restrict__ cand,
                                                    int* __restrict__ knn,
                                                    float* __restrict__ xout) {
    const int tid  = threadIdx.x;
    const int g    = tid >> 7;          // 8 groups
    const int l    = tid & 127;         // 128 threads/group
    const int lane = tid & 63;
    const int wv   = (tid >> 6) & 1;    // wave within group
    const int nun  = meta[0], cs = meta[1], cl = meta[2];
    const int nchunks = (nun + 7) >> 3;

    __shared__ int    sknn[8][16];
    __shared__ uint64 gm[8][2];
    __shared__ uint64 swin[8];
    __shared__ float  gbuf[8][68];
    __shared__ float  psum[8][128];
    __shared__ float  psq[8][128];
    __shared__ float  ssum[128], ssq[128];
    __shared__ float  ssc[128], ssh[128];

    if (tid < 128) { ssum[tid] = 0.f; ssq[tid] = 0.f; }
    __syncthreads();

    float h[KNN];

    for (int chunk = 0; chunk < nchunks; ++chunk) {
        const int  c    = chunk*8 + g;
        const bool act  = (c < nun);
        const bool fast = act && (c < MAXC);

        // ---- phase A: merge 2048 candidates (or slow full scan) ----
        uint64 kc[16];
        if (fast) {
            const uint64* src = cand + ((size_t)c << 11);
#pragma unroll
            for (int j = 0; j < 16; ++j) kc[j] = src[l + (j << 7)];
        }
        float sqx = 0.f, sqy = 0.f, sqz = 0.f;
        if (act && !fast) {
            const int cpt = fps[c];
            sqx = p[3*cpt]; sqy = p[3*cpt+1]; sqz = p[3*cpt+2];
        }
        uint64 lastv = 0ull;
        for (int r = 0; r < KNN; ++r) {
            uint64 m = ~0ull;
            if (fast) {
#pragma unroll
                for (int j = 0; j < 16; ++j) {
                    const uint64 v = kc[j];
                    if (v > lastv && v < m) m = v;
                }
            } else if (act) {
                for (int i = l; i < N_PTS; i += 128) {
                    float dx = p[3*i]   - sqx;
                    float dy = p[3*i+1] - sqy;
                    float dz = p[3*i+2] - sqz;
                    float d  = fmaf(dx, dx, fmaf(dy, dy, dz*dz));
                    uint64 v = ((uint64)dist_key(d) << 32) | (uint32)i;
                    if (v > lastv && v < m) m = v;
                }
            }
#pragma unroll
            for (int off = 32; off > 0; off >>= 1) {
                uint64 o = __shfl_xor(m, off);
                if (o < m) m = o;
            }
            if (lane == 0) gm[g][wv] = m;
            __syncthreads();
            if (l == 0) {
                uint64 w = gm[g][0] < gm[g][1] ? gm[g][0] : gm[g][1];
                swin[g] = w;
                if (act) {
                    const int wi = (int)(w & 0xFFFFFFFFull);
                    sknn[g][r] = wi;
                    knn[c*KNN + r] = wi;
                }
            }
            __syncthreads();
            lastv = swin[g];
        }

        // ---- phase B: h once into regs, accumulate stats ----
        float ls = 0.f, lq = 0.f;
#pragma unroll
        for (int k = 0; k < KNN; ++k) {
            if (act && l < GDIM) {
                const int pt = sknn[g][k];
                gbuf[g][l] = (l < 3) ? p[3*pt + l] : x[(pt << 6) + l - 3];
            }
            __syncthreads();
            float acc = 0.f;
            if (act) {
#pragma unroll
                for (int cc = 0; cc < GDIM; ++cc)
                    acc = fmaf(gbuf[g][cc], W[cc*C_OUT + l], acc);
            }
            h[k] = acc;
            ls += acc;
            lq = fmaf(acc, acc, lq);
            __syncthreads();
        }
        const float cf = act ? (float)slot_count(c, nun, cs, cl, M_PTS) : 0.f;
        psum[g][l] = cf * ls;
        psq[g][l]  = cf * lq;
        __syncthreads();
        if (tid < 128) {
            float a = 0.f, b = 0.f;
#pragma unroll
            for (int gg = 0; gg < 8; ++gg) { a += psum[gg][tid]; b += psq[gg][tid]; }
            ssum[tid] += a; ssq[tid] += b;
        }
        __syncthreads();
    }

    // ---- phase C: BN finalize ----
    if (tid < 128) {
        const float inv = 1.0f / (float)(M_PTS * KNN);
        const float mean = ssum[tid] * inv;
        const float var  = ssq[tid] * inv - mean*mean;
        const float sc   = gamma[tid] * rsqrtf(var + BN_EPS);
        ssc[tid] = sc;
        ssh[tid] = fmaf(-mean, sc, beta[tid]);
    }
    __syncthreads();

    // ---- phase D: pooled output rows ----
    if (nchunks == 1) {
        if (g < nun) {
            const float sc = ssc[l], sh = ssh[l];
            float mx = 0.f;   // max_k relu(y) == max(0, max_k y)
#pragma unroll
            for (int k = 0; k < KNN; ++k) mx = fmaxf(mx, fmaf(h[k], sc, sh));
            xout[g*C_OUT + l] = mx;
        }
    } else {
        // generic recompute path (uniform barriers)
        for (int chunk = 0; chunk < nchunks; ++chunk) {
            const int  c   = chunk*8 + g;
            const bool act = (c < nun);
            const float sc = ssc[l], sh = ssh[l];
            float mx = 0.f;
#pragma unroll
            for (int k = 0; k < KNN; ++k) {
                if (act && l < GDIM) {
                    const int pt = knn[c*KNN + k];
                    gbuf[g][l] = (l < 3) ? p[3*pt + l] : x[(pt << 6) + l - 3];
                }
                __syncthreads();
                float acc = 0.f;
                if (act) {
#pragma unroll
                    for (int cc = 0; cc < GDIM; ++cc)
                        acc = fmaf(gbuf[g][cc], W[cc*C_OUT + l], acc);
                }
                mx = fmaxf(mx, fmaf(acc, sc, sh));
                __syncthreads();
            }
            if (act) xout[c*C_OUT + l] = mx;
        }
    }
}

// ---- broadcast periodic rows: xout[m] = xout[slot(m)] for m >= nuniq (float4) ----
__global__ void __launch_bounds__(256) bcast_kernel(const int* __restrict__ meta,
                                                    float* __restrict__ xout) {
    const int nun = meta[0], cs = meta[1], cl = meta[2];
    const int idx = blockIdx.x * 256 + threadIdx.x;      // float4 index
    const int m = nun + (idx >> 5);                      // 32 float4 per row
    if (m >= M_PTS) return;
    const int c4 = idx & 31;
    const int sl = cs + (m - cs) % cl;
    float4 v = ((const float4*)xout)[sl*32 + c4];
    ((float4*)xout)[(size_t)m*32 + c4] = v;
}

extern "C" void kernel_launch(void* const* d_in, const int* in_sizes, int n_in,
                              void* d_out, int out_size, void* d_ws, size_t ws_size,
                              hipStream_t stream) {
    (void)in_sizes; (void)n_in; (void)out_size; (void)ws_size;
    const float* p     = (const float*)d_in[0];
    const float* x     = (const float*)d_in[1];
    // d_in[2] = o (unused)
    const float* W     = (const float*)d_in[3];
    const float* gamma = (const float*)d_in[4];
    const float* beta  = (const float*)d_in[5];

    float* out  = (float*)d_out;
    float* newp = out;               // [M_PTS, 3]
    float* xout = out + M_PTS * 3;   // [M_PTS, C_OUT]

    char* ws = (char*)d_ws;
    int*    fps   = (int*)   (ws + OFF_FPS);
    int*    meta  = (int*)   (ws + OFF_META);
    int*    knn   = (int*)   (ws + OFF_KNN);
    uint64* cand  = (uint64*)(ws + OFF_CAND);

    fps_chain_kernel<<<1, 1024, 0, stream>>>(p, fps, meta);
    knn_part_kernel <<<128, 1024, 0, stream>>>(p, fps, meta, cand, newp);
    tail_kernel     <<<1, 1024, 0, stream>>>(p, x, W, gamma, beta, fps, meta,
                                             cand, knn, xout);
    bcast_kernel    <<<M_PTS*32/256, 256, 0, stream>>>(meta, xout);
}

// Round 9
// 69.040 us; speedup vs baseline: 3.1020x; 3.1020x over previous
//
#include <hip/hip_runtime.h>

#define N_PTS 32768
#define M_PTS 8192      // N / STRIDE
#define C_IN  64
#define C_OUT 128
#define KNN   16
#define GDIM  67        // 3 + C_IN
#define BN_EPS 1e-5f
#define SBLK  64        // merge_stats grid
#define MAXC  64        // centers with candidate/hbuf fast path

// workspace offsets (bytes)
#define OFF_FPS   0u          // int[M_PTS] (only first nuniq used)
#define OFF_META  32768u      // int[8]: [0]=nuniq [1]=cycStart [2]=cycLen
#define OFF_KNN   33024u      // int[M_PTS*KNN]
#define OFF_CAND  557312u     // u64[MAXC*2048]
#define OFF_HBUF  1605888u    // float[MAXC*KNN*C_OUT]
#define OFF_PART  2130176u    // float[SBLK*256]
#define OFF_SCALE 2195712u    // float[C_OUT]
#define OFF_SHIFT 2196224u    // float[C_OUT]

typedef unsigned int uint32;
typedef unsigned long long uint64;

// multiplicity of unique slot s in the length-M periodic index sequence
__device__ __forceinline__ int slot_count(int s, int nun, int cs, int cl, int M) {
    if (s < cs) return 1;                 // pre-cycle slot: occurs once
    const int E = M - nun;                // extended (periodic) occurrences
    const int base = E / cl, rem = E % cl;
    const int start = (nun - cs) % cl;    // residue of first extended index
    int off = (s - cs) - start; if (off < 0) off += cl;
    return 1 + base + (off < rem ? 1 : 0);
}

__device__ __forceinline__ uint32 dist_key(float d) {
    uint32 u = __float_as_uint(d);
    return (u & 0x80000000u) ? ~u : (u | 0x80000000u);
}

// ---------------- FPS chain only: serial argmax steps, LDS chain ----------------
__global__ void __launch_bounds__(1024) fps_chain_kernel(const float* __restrict__ p,
                                                         int* __restrict__ fps,
                                                         int* __restrict__ meta) {
    __shared__ int   s_chain[M_PTS];     // 32 KB
    __shared__ float wv_d[16];
    __shared__ int   wv_i[16];
    __shared__ int s_last, s_done, s_cs, s_win, s_found;
    const int tid  = threadIdx.x;
    const int lane = tid & 63;
    const int wid  = tid >> 6;

    if (tid == 0) { s_chain[0] = 0; s_last = 0; s_done = 0; s_cs = 0; }
    __syncthreads();

    int t = 1;
    while (t < M_PTS) {
        const int last = s_last;
        const float qx = p[3*last], qy = p[3*last+1], qz = p[3*last+2];
        float bd = -1.0f; int bi = 0;
#pragma unroll
        for (int j = 0; j < 32; ++j) {
            const int i = tid + (j << 10);
            // match numpy: ((dx^2 + dy^2) + dz^2), no FMA contraction
            float dx = __fsub_rn(p[3*i],   qx);
            float dy = __fsub_rn(p[3*i+1], qy);
            float dz = __fsub_rn(p[3*i+2], qz);
            float d  = __fadd_rn(__fadd_rn(__fmul_rn(dx,dx), __fmul_rn(dy,dy)),
                                 __fmul_rn(dz,dz));
            if (d > bd) { bd = d; bi = i; }   // ascending i keeps first on ties
        }
#pragma unroll
        for (int off = 32; off > 0; off >>= 1) {
            float od = __shfl_xor(bd, off);
            int   oi = __shfl_xor(bi, off);
            if (od > bd || (od == bd && oi < bi)) { bd = od; bi = oi; }
        }
        if (lane == 0) { wv_d[wid] = bd; wv_i[wid] = bi; }
        __syncthreads();
        if (wid == 0) {
            float rd = (lane < 16) ? wv_d[lane] : -1.0f;
            int   ri = (lane < 16) ? wv_i[lane] : 0x7fffffff;
#pragma unroll
            for (int off = 8; off > 0; off >>= 1) {
                float od = __shfl_xor(rd, off);
                int   oi = __shfl_xor(ri, off);
                if (od > rd || (od == rd && oi < ri)) { rd = od; ri = oi; }
            }
            if (lane == 0) { s_win = ri; s_found = -1; }
        }
        __syncthreads();
        const int nxt = s_win;
        for (int i = tid; i < t; i += 1024)
            if (s_chain[i] == nxt) s_found = i;
        __syncthreads();
        if (tid == 0) {
            if (s_found >= 0) { s_cs = s_found; s_done = 1; }
            else { s_chain[t] = nxt; s_last = nxt; }
        }
        __syncthreads();
        if (s_done) break;
        ++t;
    }

    if (tid == 0) {
        if (s_done) { meta[0] = t; meta[1] = s_cs; meta[2] = t - s_cs; }
        else        { meta[0] = M_PTS; meta[1] = 0; meta[2] = 1; }
    }
    const int nun = s_done ? t : M_PTS;
    for (int i = tid; i < nun; i += 1024) fps[i] = s_chain[i];
}

// ---- kNN phase A (+ parallel newp fill): 8 slices/center, per-wave top-16 ------
__global__ void __launch_bounds__(1024) knn_part_kernel(const float* __restrict__ p,
                                                        const int* __restrict__ fps,
                                                        const int* __restrict__ meta,
                                                        uint64* __restrict__ cand,
                                                        float* __restrict__ newp) {
    const int tid   = threadIdx.x;
    const int lane  = tid & 63;
    const int wid   = tid >> 6;           // 16 waves
    const int slice = blockIdx.x & 7;
    const int c0    = blockIdx.x >> 3;    // 16 center groups
    const int nun   = meta[0];
    const int cs    = meta[1], cl = meta[2];

    // parallel newp fill
    for (int e = blockIdx.x * 1024 + tid; e < M_PTS; e += gridDim.x * 1024) {
        const int sl = (e < nun) ? e : cs + (e - cs) % cl;
        const int id = fps[sl];
        newp[3*e]   = p[3*id];
        newp[3*e+1] = p[3*id+1];
        newp[3*e+2] = p[3*id+2];
    }

    for (int c = c0; c < nun && c < MAXC; c += 16) {
        const int cpt = fps[c];
        const float qx = p[3*cpt], qy = p[3*cpt+1], qz = p[3*cpt+2];
        const int base = slice << 12;     // slice*4096

        uint64 pk4[4];
#pragma unroll
        for (int j = 0; j < 4; ++j) {
            const int i = base + tid + (j << 10);
            float dx = p[3*i]   - qx;
            float dy = p[3*i+1] - qy;
            float dz = p[3*i+2] - qz;
            float d  = fmaf(dx, dx, fmaf(dy, dy, dz*dz));
            pk4[j] = ((uint64)dist_key(d) << 32) | (uint32)i;
        }

        uint64 lastv = 0ull;
        uint64* out = cand + ((size_t)c << 11) + (slice << 8) + (wid << 4);
        for (int r = 0; r < KNN; ++r) {
            uint64 m = ~0ull;
#pragma unroll
            for (int j = 0; j < 4; ++j) {
                const uint64 v = pk4[j];
                if (v > lastv && v < m) m = v;
            }
#pragma unroll
            for (int off = 32; off > 0; off >>= 1) {
                uint64 o = __shfl_xor(m, off);
                if (o < m) m = o;
            }
            if (lane == 0) out[r] = m;
            lastv = m;
        }
    }
}

// ---- merge + stats: 64 blocks x 128 threads. Per center: merge 2048 cands,
// write knn, compute h once (stored to hbuf), accumulate weighted partials. ----
__global__ void __launch_bounds__(128) merge_stats_kernel(const float* __restrict__ p,
                                                          const float* __restrict__ x,
                                                          const float* __restrict__ W,
                                                          const int* __restrict__ fps,
                                                          const int* __restrict__ meta,
                                                          const uint64* __restrict__ cand,
                                                          int* __restrict__ knn,
                                                          float* __restrict__ hbuf,
                                                          float* __restrict__ part) {
    const int tid  = threadIdx.x;       // == channel
    const int lane = tid & 63;
    const int wv   = tid >> 6;          // 2 waves
    const int nun  = meta[0], cs = meta[1], cl = meta[2];

    __shared__ int    sknn[KNN];
    __shared__ uint64 wmin[2];
    __shared__ uint64 s_win;
    __shared__ float  gbuf[GDIM+1];

    float s_sum = 0.f, s_sq = 0.f;

    for (int c = blockIdx.x; c < nun; c += SBLK) {
        // ---- merge (fast: candidate buffer; slow: full rescan) ----
        if (c < MAXC) {
            uint64 kc[16];
            const uint64* src = cand + ((size_t)c << 11);
#pragma unroll
            for (int j = 0; j < 16; ++j) kc[j] = src[tid + (j << 7)];
            uint64 lastv = 0ull;
            for (int r = 0; r < KNN; ++r) {
                uint64 m = ~0ull;
#pragma unroll
                for (int j = 0; j < 16; ++j) {
                    const uint64 v = kc[j];
                    if (v > lastv && v < m) m = v;
                }
#pragma unroll
                for (int off = 32; off > 0; off >>= 1) {
                    uint64 o = __shfl_xor(m, off);
                    if (o < m) m = o;
                }
                if (lane == 0) wmin[wv] = m;
                __syncthreads();
                if (tid == 0) {
                    uint64 w = wmin[0] < wmin[1] ? wmin[0] : wmin[1];
                    s_win = w;
                    const int wi = (int)(w & 0xFFFFFFFFull);
                    sknn[r] = wi;
                    knn[c*KNN + r] = wi;
                }
                __syncthreads();
                lastv = s_win;
            }
        } else {
            const int cpt = fps[c];
            const float qx = p[3*cpt], qy = p[3*cpt+1], qz = p[3*cpt+2];
            uint64 lastv = 0ull;
            for (int r = 0; r < KNN; ++r) {
                uint64 m = ~0ull;
                for (int i = tid; i < N_PTS; i += 128) {
                    float dx = p[3*i]   - qx;
                    float dy = p[3*i+1] - qy;
                    float dz = p[3*i+2] - qz;
                    float d  = fmaf(dx, dx, fmaf(dy, dy, dz*dz));
                    uint64 v = ((uint64)dist_key(d) << 32) | (uint32)i;
                    if (v > lastv && v < m) m = v;
                }
#pragma unroll
                for (int off = 32; off > 0; off >>= 1) {
                    uint64 o = __shfl_xor(m, off);
                    if (o < m) m = o;
                }
                if (lane == 0) wmin[wv] = m;
                __syncthreads();
                if (tid == 0) {
                    uint64 w = wmin[0] < wmin[1] ? wmin[0] : wmin[1];
                    s_win = w;
                    const int wi = (int)(w & 0xFFFFFFFFull);
                    sknn[r] = wi;
                    knn[c*KNN + r] = wi;
                }
                __syncthreads();
                lastv = s_win;
            }
        }

        // ---- h once per (k, channel); store; accumulate stats ----
        float ls = 0.f, lq = 0.f;
#pragma unroll
        for (int k = 0; k < KNN; ++k) {
            const int pt = sknn[k];
            if (tid < GDIM) gbuf[tid] = (tid < 3) ? p[3*pt + tid]
                                                  : x[(pt << 6) + tid - 3];
            __syncthreads();
            float acc = 0.f;
#pragma unroll
            for (int cc = 0; cc < GDIM; ++cc)
                acc = fmaf(gbuf[cc], W[cc*C_OUT + tid], acc);
            if (c < MAXC) hbuf[((c << 4) + k)*C_OUT + tid] = acc;
            ls += acc;
            lq = fmaf(acc, acc, lq);
            __syncthreads();
        }
        const float cf = (float)slot_count(c, nun, cs, cl, M_PTS);
        s_sum = fmaf(cf, ls, s_sum);
        s_sq  = fmaf(cf, lq, s_sq);
    }
    part[blockIdx.x*256 + tid]       = s_sum;
    part[blockIdx.x*256 + 128 + tid] = s_sq;
}

// ---------------- finalize BN: scale/shift per channel ----------------
__global__ void __launch_bounds__(128) bnfin_kernel(const float* __restrict__ part,
                                                    const float* __restrict__ gamma,
                                                    const float* __restrict__ beta,
                                                    float* __restrict__ scale,
                                                    float* __restrict__ shift) {
    const int t = threadIdx.x;
    float s = 0.f, q = 0.f;
    for (int b = 0; b < SBLK; ++b) {
        s += part[b*256 + t];
        q += part[b*256 + 128 + t];
    }
    const float inv = 1.0f / (float)(M_PTS * KNN);
    const float mean = s * inv;
    const float var  = q * inv - mean*mean;
    const float sc   = gamma[t] * rsqrtf(var + BN_EPS);
    scale[t] = sc;
    shift[t] = fmaf(-mean, sc, beta[t]);
}

// ---- final: all M rows from cached h: BN + relu + maxpool, write xout --------
__global__ void __launch_bounds__(256) final_out_kernel(const float* __restrict__ p,
                                                        const float* __restrict__ x,
                                                        const float* __restrict__ W,
                                                        const int* __restrict__ knn,
                                                        const int* __restrict__ meta,
                                                        const float* __restrict__ hbuf,
                                                        const float* __restrict__ scale,
                                                        const float* __restrict__ shift,
                                                        float* __restrict__ xout) {
    const int nun = meta[0], cs = meta[1], cl = meta[2];
    const int idx = blockIdx.x * 256 + threadIdx.x;   // (row m, quad c4)
    const int m = idx >> 5;
    if (m >= M_PTS) return;
    const int c4 = idx & 31;                          // 4 channels per thread
    const int sl = (m < nun) ? m : cs + (m - cs) % cl;

    float4 o;
    float* ov = (float*)&o;
    if (sl < MAXC) {
        const float* hb = hbuf + (sl << 4)*C_OUT;
#pragma unroll
        for (int cc = 0; cc < 4; ++cc) {
            const int ch = c4*4 + cc;
            const float sc = scale[ch], sh = shift[ch];
            float mx = 0.f;   // max_k relu(y) == max(0, max_k y)
#pragma unroll
            for (int k = 0; k < KNN; ++k)
                mx = fmaxf(mx, fmaf(hb[k*C_OUT + ch], sc, sh));
            ov[cc] = mx;
        }
    } else {
        // correctness fallback: recompute h from knn/W (never hit for small nuniq)
#pragma unroll
        for (int cc = 0; cc < 4; ++cc) {
            const int ch = c4*4 + cc;
            const float sc = scale[ch], sh = shift[ch];
            float mx = 0.f;
            for (int k = 0; k < KNN; ++k) {
                const int pt = knn[sl*KNN + k];
                float acc = 0.f;
                acc = fmaf(p[3*pt],   W[0*C_OUT + ch], acc);
                acc = fmaf(p[3*pt+1], W[1*C_OUT + ch], acc);
                acc = fmaf(p[3*pt+2], W[2*C_OUT + ch], acc);
                for (int cx = 0; cx < C_IN; ++cx)
                    acc = fmaf(x[(pt << 6) + cx], W[(3+cx)*C_OUT + ch], acc);
                mx = fmaxf(mx, fmaf(acc, sc, sh));
            }
            ov[cc] = mx;
        }
    }
    ((float4*)xout)[(size_t)m*32 + c4] = o;
}

extern "C" void kernel_launch(void* const* d_in, const int* in_sizes, int n_in,
                              void* d_out, int out_size, void* d_ws, size_t ws_size,
                              hipStream_t stream) {
    (void)in_sizes; (void)n_in; (void)out_size; (void)ws_size;
    const float* p     = (const float*)d_in[0];
    const float* x     = (const float*)d_in[1];
    // d_in[2] = o (unused)
    const float* W     = (const float*)d_in[3];
    const float* gamma = (const float*)d_in[4];
    const float* beta  = (const float*)d_in[5];

    float* out  = (float*)d_out;
    float* newp = out;               // [M_PTS, 3]
    float* xout = out + M_PTS * 3;   // [M_PTS, C_OUT]

    char* ws = (char*)d_ws;
    int*    fps   = (int*)   (ws + OFF_FPS);
    int*    meta  = (int*)   (ws + OFF_META);
    int*    knn   = (int*)   (ws + OFF_KNN);
    uint64* cand  = (uint64*)(ws + OFF_CAND);
    float*  hbuf  = (float*) (ws + OFF_HBUF);
    float*  part  = (float*) (ws + OFF_PART);
    float*  scale = (float*) (ws + OFF_SCALE);
    float*  shift = (float*) (ws + OFF_SHIFT);

    fps_chain_kernel <<<1, 1024, 0, stream>>>(p, fps, meta);
    knn_part_kernel  <<<128, 1024, 0, stream>>>(p, fps, meta, cand, newp);
    merge_stats_kernel<<<SBLK, 128, 0, stream>>>(p, x, W, fps, meta, cand,
                                                 knn, hbuf, part);
    bnfin_kernel     <<<1, 128, 0, stream>>>(part, gamma, beta, scale, shift);
    final_out_kernel <<<M_PTS*32/256, 256, 0, stream>>>(p, x, W, knn, meta, hbuf,
                                                        scale, shift, xout);
}